// Round 6
// baseline (495.025 us; speedup 1.0000x reference)
//
#include <hip/hip_runtime.h>
#include <stdint.h>

// Problem constants
#define Bn 8
#define Tn 2048
#define Cn 1024
#define Mn (Bn * Tn)
#define NTB 72     // causal 128(t)x256(s) tiles per batch: sum(qt/2+1) = 72
#define NST 8      // max 256-wide s-tiles per row

typedef __attribute__((ext_vector_type(4))) float f32x4;
typedef _Float16 f16;
typedef __attribute__((ext_vector_type(8))) _Float16 f16x8;
typedef uint16_t u16;
typedef uint32_t u32;

static __device__ __forceinline__ u16 f2h(float f) {
  union { f16 h; u16 u; } c; c.h = (f16)f; return c.u;
}
static __device__ __forceinline__ f32x4 mfmaH(f16x8 a, f16x8 b, f32x4 c) {
  return __builtin_amdgcn_mfma_f32_16x16x32_f16(a, b, c, 0, 0, 0);
}
// async global->LDS, 16B/lane; LDS dest = wave-uniform base + lane*16.
static __device__ __forceinline__ void gld16(const void* g, void* l) {
  __builtin_amdgcn_global_load_lds(
      (const __attribute__((address_space(1))) u32*)g,
      (__attribute__((address_space(3))) u32*)l, 16, 0, 0);
}
// tiles before row-tile qt (256-wide s-tiles, causal)
static __device__ __forceinline__ int tri_off(int qt) {
  int a = qt >> 1;
  return (qt & 1) ? (a + 1) * (a + 1) : a * (a + 1);
}

// ---------------------------------------------------------------------------
// ksplitW: W fp32 -> fp16 hi only.
// ---------------------------------------------------------------------------
__global__ __launch_bounds__(256) void ksplitW(const float* __restrict__ s,
                                               u16* __restrict__ hi) {
  size_t i = ((size_t)blockIdx.x * 256 + threadIdx.x) * 8;
  float4 a = *(const float4*)(s + i), b = *(const float4*)(s + i + 4);
  float f[8] = {a.x, a.y, a.z, a.w, b.x, b.y, b.z, b.w};
  union { u16 u[8]; uint4 v; } H;
#pragma unroll
  for (int j = 0; j < 8; ++j) H.u[j] = f2h(f[j]);
  *(uint4*)(hi + i) = H.v;
}

// ---------------------------------------------------------------------------
// ksplitX: x fp32 -> fp16 hi + fp16 lo residual (~22-bit effective).
// ---------------------------------------------------------------------------
__global__ __launch_bounds__(256) void ksplitX(const float* __restrict__ s,
                                               u16* __restrict__ hi,
                                               u16* __restrict__ lo) {
  size_t i = ((size_t)blockIdx.x * 256 + threadIdx.x) * 8;
  float4 a = *(const float4*)(s + i), b = *(const float4*)(s + i + 4);
  float f[8] = {a.x, a.y, a.z, a.w, b.x, b.y, b.z, b.w};
  union { u16 u[8]; uint4 v; } H, L;
#pragma unroll
  for (int j = 0; j < 8; ++j) {
    f16 h = (f16)f[j];
    union { f16 h; u16 u; } ch; ch.h = h;
    H.u[j] = ch.u;
    L.u[j] = f2h(f[j] - (float)h);
  }
  *(uint4*)(hi + i) = H.v;
  *(uint4*)(lo + i) = L.v;
}

// ---------------------------------------------------------------------------
// K1: xh = x_h @ W_h^T. 128x256 tile (wave 64x128), BK=64 as 2 half-planes.
// ---------------------------------------------------------------------------
__global__ __launch_bounds__(256) void k1_xh(const u16* __restrict__ x_h,
                                             const u16* __restrict__ W_h,
                                             u16* __restrict__ xh) {
  __shared__ __align__(16) u16 Ah[8192], Bh[16384];
  const int tid = threadIdx.x;
  const int m0 = blockIdx.x * 128, n0 = blockIdx.y * 256;
  const int wave = tid >> 6, lane = tid & 63;
  const int wrow = (wave >> 1) * 64, wcol = (wave & 1) * 128;
  const int quad = lane >> 4, l16 = lane & 15;

  f32x4 acc[4][8] = {};

  for (int k0 = 0; k0 < Cn; k0 += 64) {
#pragma unroll
    for (int i = 0; i < 4; ++i) {
      int chunk = i * 256 + tid;
      int kk = chunk >> 9, row = (chunk >> 2) & 127, c8 = (chunk & 3) * 8;
      gld16(x_h + (size_t)(m0 + row) * Cn + k0 + kk * 32 + c8, Ah + kk * 4096 + row * 32 + c8);
    }
#pragma unroll
    for (int i = 0; i < 8; ++i) {
      int chunk = i * 256 + tid;
      int kk = chunk >> 10, row = (chunk >> 2) & 255, c8 = (chunk & 3) * 8;
      gld16(W_h + (size_t)(n0 + row) * Cn + k0 + kk * 32 + c8, Bh + kk * 8192 + row * 32 + c8);
    }
    __syncthreads();
#pragma unroll
    for (int kk = 0; kk < 2; ++kk) {
      f16x8 a[4], b[8];
#pragma unroll
      for (int i = 0; i < 4; ++i)
        a[i] = *(const f16x8*)(Ah + kk * 4096 + (wrow + i * 16 + l16) * 32 + quad * 8);
#pragma unroll
      for (int j = 0; j < 8; ++j)
        b[j] = *(const f16x8*)(Bh + kk * 8192 + (wcol + j * 16 + l16) * 32 + quad * 8);
#pragma unroll
      for (int mi = 0; mi < 4; ++mi)
#pragma unroll
        for (int ni = 0; ni < 8; ++ni)
          acc[mi][ni] = mfmaH(a[mi], b[ni], acc[mi][ni]);
    }
    __syncthreads();
  }
#pragma unroll
  for (int mi = 0; mi < 4; ++mi)
#pragma unroll
    for (int ni = 0; ni < 8; ++ni)
#pragma unroll
      for (int r = 0; r < 4; ++r) {
        int row = wrow + mi * 16 + quad * 4 + r;
        int col = wcol + ni * 16 + l16;
        xh[(size_t)(m0 + row) * Cn + n0 + col] = f2h(acc[mi][ni][r]);
      }
}

// ---------------------------------------------------------------------------
// K2: S = (x_h + x_l) @ xh^T on causal 128(t)x256(s) tiles, BK=32; lazy
// softmax: P = exp(S - m_tile) fp16, packed tile storage; stats per 256-tile.
// ---------------------------------------------------------------------------
__global__ __launch_bounds__(256) void k2_scores(const u16* __restrict__ x_h,
                                                 const u16* __restrict__ x_l,
                                                 const u16* __restrict__ xh,
                                                 u16* __restrict__ P,
                                                 float* __restrict__ mt,
                                                 float* __restrict__ lt) {
  __shared__ __align__(16) union {
    struct { u16 Ah[4096], Al[4096], Bh[8192]; } s;
    struct { float Mrow[2][128]; float Lrow[2][128]; } e;
  } u;
  const int tid = threadIdx.x;
  const int bL = blockIdx.y;
  const int lin = blockIdx.x;
  int qt = 0, base = 0;
  while (base + (qt >> 1) + 1 <= lin) { base += (qt >> 1) + 1; qt++; }
  const int st2 = lin - base;
  const int t0 = qt * 128, s0 = st2 * 256;
  const int wave = tid >> 6, lane = tid & 63;
  const int wrow = (wave >> 1) * 64, wcol = (wave & 1) * 128;
  const int quad = lane >> 4, l16 = lane & 15;

  f32x4 acc[4][8] = {};

  for (int k0 = 0; k0 < Cn; k0 += 32) {
#pragma unroll
    for (int i = 0; i < 2; ++i) {
      int chunk = i * 256 + tid;
      int row = chunk >> 2, c8 = (chunk & 3) * 8;
      size_t g = ((size_t)bL * Tn + t0 + row) * Cn + k0 + c8;
      gld16(x_h + g, u.s.Ah + row * 32 + c8);
      gld16(x_l + g, u.s.Al + row * 32 + c8);
    }
#pragma unroll
    for (int i = 0; i < 4; ++i) {
      int chunk = i * 256 + tid;
      int row = chunk >> 2, c8 = (chunk & 3) * 8;
      gld16(xh + ((size_t)bL * Tn + s0 + row) * Cn + k0 + c8, u.s.Bh + row * 32 + c8);
    }
    __syncthreads();
    f16x8 a_h[4], a_l[4], b[8];
#pragma unroll
    for (int i = 0; i < 4; ++i) {
      a_h[i] = *(const f16x8*)(u.s.Ah + (wrow + i * 16 + l16) * 32 + quad * 8);
      a_l[i] = *(const f16x8*)(u.s.Al + (wrow + i * 16 + l16) * 32 + quad * 8);
    }
#pragma unroll
    for (int j = 0; j < 8; ++j)
      b[j] = *(const f16x8*)(u.s.Bh + (wcol + j * 16 + l16) * 32 + quad * 8);
#pragma unroll
    for (int mi = 0; mi < 4; ++mi)
#pragma unroll
      for (int ni = 0; ni < 8; ++ni) {
        acc[mi][ni] = mfmaH(a_h[mi], b[ni], acc[mi][ni]);
        acc[mi][ni] = mfmaH(a_l[mi], b[ni], acc[mi][ni]);
      }
    __syncthreads();
  }

  // ---- epilogue: mask, per-row max, exp, stats, packed-P write ----
  float rm[4][4];
#pragma unroll
  for (int mi = 0; mi < 4; ++mi)
#pragma unroll
    for (int r = 0; r < 4; ++r) {
      int row = wrow + mi * 16 + quad * 4 + r;
      float m = -1e30f;
#pragma unroll
      for (int ni = 0; ni < 8; ++ni) {
        int col = wcol + ni * 16 + l16;
        if (s0 + col >= t0 + row) acc[mi][ni][r] = -1e30f;
        m = fmaxf(m, acc[mi][ni][r]);
      }
      m = fmaxf(m, __shfl_xor(m, 1));
      m = fmaxf(m, __shfl_xor(m, 2));
      m = fmaxf(m, __shfl_xor(m, 4));
      m = fmaxf(m, __shfl_xor(m, 8));
      rm[mi][r] = m;
    }
  if (l16 == 0) {
#pragma unroll
    for (int mi = 0; mi < 4; ++mi)
#pragma unroll
      for (int r = 0; r < 4; ++r)
        u.e.Mrow[wave & 1][wrow + mi * 16 + quad * 4 + r] = rm[mi][r];
  }
  __syncthreads();
  float rs[4][4];
#pragma unroll
  for (int mi = 0; mi < 4; ++mi)
#pragma unroll
    for (int r = 0; r < 4; ++r) {
      int row = wrow + mi * 16 + quad * 4 + r;
      float m2 = fmaxf(u.e.Mrow[0][row], u.e.Mrow[1][row]);
      float s = 0.f;
#pragma unroll
      for (int ni = 0; ni < 8; ++ni) {
        int col = wcol + ni * 16 + l16;
        float p = (s0 + col < t0 + row) ? __expf(acc[mi][ni][r] - m2) : 0.0f;
        acc[mi][ni][r] = p;
        s += p;
      }
      s += __shfl_xor(s, 1);
      s += __shfl_xor(s, 2);
      s += __shfl_xor(s, 4);
      s += __shfl_xor(s, 8);
      rs[mi][r] = s;
      rm[mi][r] = m2;
    }
  if (l16 == 0) {
#pragma unroll
    for (int mi = 0; mi < 4; ++mi)
#pragma unroll
      for (int r = 0; r < 4; ++r)
        u.e.Lrow[wave & 1][wrow + mi * 16 + quad * 4 + r] = rs[mi][r];
  }
  __syncthreads();
  if ((wave & 1) == 0 && l16 == 0) {
#pragma unroll
    for (int mi = 0; mi < 4; ++mi)
#pragma unroll
      for (int r = 0; r < 4; ++r) {
        int row = wrow + mi * 16 + quad * 4 + r;
        size_t rI = (size_t)bL * Tn + t0 + row;
        mt[rI * NST + st2] = rm[mi][r];
        lt[rI * NST + st2] = u.e.Lrow[0][row] + u.e.Lrow[1][row];
      }
  }
  const size_t pbase = (size_t)(bL * NTB + lin) * 32768;
#pragma unroll
  for (int mi = 0; mi < 4; ++mi)
#pragma unroll
    for (int ni = 0; ni < 8; ++ni)
#pragma unroll
      for (int r = 0; r < 4; ++r) {
        int row = wrow + mi * 16 + quad * 4 + r;
        int col = wcol + ni * 16 + l16;
        P[pbase + row * 256 + col] = f2h(acc[mi][ni][r]);
      }
}

// ---------------------------------------------------------------------------
// K3: per-row global max M and inverse denom Li. Row t=0 -> Li=0.
// ---------------------------------------------------------------------------
__global__ __launch_bounds__(256) void k3_stats(const float* __restrict__ mt,
                                                const float* __restrict__ lt,
                                                float* __restrict__ Mr,
                                                float* __restrict__ Li) {
  int r = blockIdx.x * 256 + threadIdx.x;
  int t = r & (Tn - 1);
  int nt = (t == 0) ? 0 : (((t - 1) >> 8) + 1);  // 256-wide tiles
  float M = -1e30f;
  for (int i = 0; i < nt; ++i) M = fmaxf(M, mt[(size_t)r * NST + i]);
  float L = 0.f;
  for (int i = 0; i < nt; ++i) L += lt[(size_t)r * NST + i] * __expf(mt[(size_t)r * NST + i] - M);
  Mr[r] = M;
  Li[r] = (L > 0.f) ? 1.f / L : 0.f;
}

// ---------------------------------------------------------------------------
// ktr: xhT[b][c][s] = xh[b][s][c]  (fp16, 128x128 LDS tiles)
// ---------------------------------------------------------------------------
__global__ __launch_bounds__(256) void ktr(const u16* __restrict__ src,
                                           u16* __restrict__ dst) {
  __shared__ __align__(16) u16 S[128 * 136];
  const int t0 = blockIdx.x * 128, c0 = blockIdx.y * 128, b = blockIdx.z;
  const int tid = threadIdx.x;
#pragma unroll
  for (int i = 0; i < 8; ++i) {
    int chunk = tid + i * 256;
    int row = chunk >> 4, c8 = (chunk & 15) * 8;
    uint4 v = *(const uint4*)(src + ((size_t)b * Tn + t0 + row) * Cn + c0 + c8);
    *(uint4*)(S + row * 136 + c8) = v;
  }
  __syncthreads();
#pragma unroll
  for (int i = 0; i < 8; ++i) {
    int chunk = tid + i * 256;
    int crow = chunk >> 4, t8 = (chunk & 15) * 8;
    union { u16 s[8]; uint4 v; } o;
#pragma unroll
    for (int j = 0; j < 8; ++j) o.s[j] = S[(t8 + j) * 136 + crow];
    *(uint4*)(dst + ((size_t)b * Cn + c0 + crow) * Tn + t0 + t8) = o.v;
  }
}

// ---------------------------------------------------------------------------
// K4: out = -( (P*alpha) @ xh ). 128(t)x256(c) tile, wave 64x128, BK=64.
// A = packed P tiles (stride 256); B = xhT; alpha per 256-wide s-tile folded
// into the A fragment.
// ---------------------------------------------------------------------------
__global__ __launch_bounds__(256) void k4_out(const u16* __restrict__ P,
                                              const u16* __restrict__ xhT,
                                              const float* __restrict__ mt,
                                              const float* __restrict__ Mr,
                                              const float* __restrict__ Li,
                                              float* __restrict__ out) {
  __shared__ __align__(16) u16 Ap[8192], Bp[16384];
  const int tid = threadIdx.x;
  const int tt = 15 - blockIdx.x;  // heavy tiles first
  const int cn = blockIdx.y, bL = blockIdx.z;
  const int t0 = tt * 128, c0 = cn * 256;
  const int wave = tid >> 6, lane = tid & 63;
  const int wrow = (wave >> 1) * 64, wcol = (wave & 1) * 128;
  const int quad = lane >> 4, l16 = lane & 15;

  f32x4 acc[4][8] = {};
  size_t rI[4]; float MrL[4], LiL[4];
#pragma unroll
  for (int mi = 0; mi < 4; ++mi) {
    rI[mi] = (size_t)bL * Tn + t0 + wrow + mi * 16 + l16;
    MrL[mi] = Mr[rI[mi]];
    LiL[mi] = Li[rI[mi]];
  }
  const size_t bbase = ((size_t)bL * Cn + c0) * Tn;
  const int off = tri_off(tt);
  const int kend = (tt + 1) * 128;

  for (int st2 = 0; st2 <= (tt >> 1); ++st2) {
    f16 ah[4];
#pragma unroll
    for (int mi = 0; mi < 4; ++mi)
      ah[mi] = (f16)(__expf(mt[rI[mi] * NST + st2] - MrL[mi]) * LiL[mi]);
    const size_t pbase = (size_t)(bL * NTB + off + st2) * 32768;
    const int klim = min(256, kend - st2 * 256);
#pragma unroll 1
    for (int kl = 0; kl < klim; kl += 64) {
#pragma unroll
      for (int i = 0; i < 4; ++i) {
        int chunk = i * 256 + tid;
        int kk = chunk >> 9, row = (chunk >> 2) & 127, c8 = (chunk & 3) * 8;
        gld16(P + pbase + (size_t)row * 256 + kl + kk * 32 + c8, Ap + kk * 4096 + row * 32 + c8);
      }
#pragma unroll
      for (int i = 0; i < 8; ++i) {
        int chunk = i * 256 + tid;
        int kk = chunk >> 10, row = (chunk >> 2) & 255, c8 = (chunk & 3) * 8;
        gld16(xhT + bbase + (size_t)row * Tn + st2 * 256 + kl + kk * 32 + c8,
              Bp + kk * 8192 + row * 32 + c8);
      }
      __syncthreads();
#pragma unroll
      for (int kk = 0; kk < 2; ++kk) {
        f16x8 a[4], b[8];
#pragma unroll
        for (int i = 0; i < 4; ++i) {
          a[i] = *(const f16x8*)(Ap + kk * 4096 + (wrow + i * 16 + l16) * 32 + quad * 8);
          f16x8 sv;
#pragma unroll
          for (int j = 0; j < 8; ++j) sv[j] = ah[i];
          a[i] = a[i] * sv;
        }
#pragma unroll
        for (int j = 0; j < 8; ++j)
          b[j] = *(const f16x8*)(Bp + kk * 8192 + (wcol + j * 16 + l16) * 32 + quad * 8);
#pragma unroll
        for (int mi = 0; mi < 4; ++mi)
#pragma unroll
          for (int ni = 0; ni < 8; ++ni)
            acc[mi][ni] = mfmaH(a[mi], b[ni], acc[mi][ni]);
      }
      __syncthreads();
    }
  }
#pragma unroll
  for (int mi = 0; mi < 4; ++mi)
#pragma unroll
    for (int ni = 0; ni < 8; ++ni)
#pragma unroll
      for (int r = 0; r < 4; ++r) {
        int row = wrow + mi * 16 + quad * 4 + r;
        int col = wcol + ni * 16 + l16;
        out[((size_t)bL * Tn + t0 + row) * Cn + c0 + col] = -acc[mi][ni][r];
      }
}

// ---------------------------------------------------------------------------
extern "C" void kernel_launch(void* const* d_in, const int* in_sizes, int n_in,
                              void* d_out, int out_size, void* d_ws, size_t ws_size,
                              hipStream_t stream) {
  (void)in_sizes; (void)n_in; (void)out_size; (void)ws_size;
  const float* x = (const float*)d_in[0];
  const float* W = (const float*)d_in[1];
  float* out = (float*)d_out;

  // workspace carve, full 8-batch: ~137 MB (proven >=140.6 available in R3/R4)
  char* p = (char*)d_ws;
  u16* x_h = (u16*)p; p += (size_t)Mn * Cn * 2;              // 33.6 MB
  u16* xLT = (u16*)p; p += (size_t)Mn * Cn * 2;              // x_l, reused as xhT
  u16* xh  = (u16*)p; p += (size_t)Mn * Cn * 2;
  u16* Pp  = (u16*)p; p += (size_t)Bn * NTB * 32768 * 2;     // 37.75 MB
  u16* W_h = (u16*)p; p += (size_t)Cn * Cn * 2;
  float* mt = (float*)p; p += (size_t)Mn * NST * 4;
  float* lt = (float*)p; p += (size_t)Mn * NST * 4;
  float* Mr = (float*)p; p += (size_t)Mn * 4;
  float* Li = (float*)p; p += (size_t)Mn * 4;

  dim3 blk(256);
  ksplitW<<<dim3((Cn * Cn) / 2048), blk, 0, stream>>>(W, W_h);
  ksplitX<<<dim3((u32)(((size_t)Mn * Cn) / 2048)), blk, 0, stream>>>(x, x_h, xLT);
  k1_xh<<<dim3(Mn / 128, Cn / 256), blk, 0, stream>>>(x_h, W_h, xh);
  k2_scores<<<dim3(NTB, Bn), blk, 0, stream>>>(x_h, xLT, xh, Pp, mt, lt);
  k3_stats<<<dim3(Mn / 256), blk, 0, stream>>>(mt, lt, Mr, Li);
  ktr<<<dim3(Tn / 128, Cn / 128, Bn), blk, 0, stream>>>(xh, xLT);
  k4_out<<<dim3(16, Cn / 256, Bn), blk, 0, stream>>>(Pp, xLT, mt, Mr, Li, out);
}